// Round 4
// baseline (505.370 us; speedup 1.0000x reference)
//
#include <hip/hip_runtime.h>

#define N_NODES 200000
#define E_EVENTS 1000000
#define D_DIM 128
#define B_BATCH 50000
#define K_NEI 20

#define SCAN_BLK 196              // ceil(200000/1024)
#define NODES_PER_WAVE 13
#define SEG_WAVES ((N_NODES + NODES_PER_WAVE - 1) / NODES_PER_WAVE)   // 15385
#define SEG_BLOCKS ((SEG_WAVES + 3) / 4)                              // 3847 -> round to group: 3848
#define ATTN_BLOCKS (B_BATCH / 4)                                     // 12500
#define N_GROUPS 962              // 962*4=3848 seg, 962*13=12506 attn block slots

// ---------------- ws layout (element offsets, 4B units) --------------------
// counts   : [0,        200000)   int
// offsets  : [200000,   400000)   int
// cursor   : [400000,   600000)   int
// blockSums: [600000,   600256)   int
// perm     : [600320,  1600320)   int
// stats    : [1600320, 1600360)   float2[20]
// partials : [1600384, 1605504)   float2[128*20]

// ---------------------------------------------------------------------------
// 1) histogram of node ids
// ---------------------------------------------------------------------------
__global__ void hist(const int* __restrict__ ids, int* __restrict__ counts)
{
    int e = blockIdx.x * blockDim.x + threadIdx.x;
    if (e < E_EVENTS) atomicAdd(counts + ids[e], 1);
}

// ---------------------------------------------------------------------------
// 2) per-block sums (1024 counts per block)
// ---------------------------------------------------------------------------
__global__ void scan_block(const int* __restrict__ counts, int* __restrict__ blockSums)
{
    __shared__ int sd[256];
    int t = threadIdx.x, base = blockIdx.x * 1024 + t * 4;
    int s = 0;
#pragma unroll
    for (int j = 0; j < 4; ++j) { int i = base + j; if (i < N_NODES) s += counts[i]; }
    sd[t] = s; __syncthreads();
    for (int off = 128; off; off >>= 1) {
        if (t < off) sd[t] += sd[t + off];
        __syncthreads();
    }
    if (t == 0) blockSums[blockIdx.x] = sd[0];
}

// ---------------------------------------------------------------------------
// 3) exclusive scan of the 196 block sums — one block, parallel.
// ---------------------------------------------------------------------------
__global__ void scan_tops(int* __restrict__ blockSums)
{
    __shared__ int sd[256];
    int t = threadIdx.x;
    int v = (t < SCAN_BLK) ? blockSums[t] : 0;
    sd[t] = v; __syncthreads();
    for (int off = 1; off < 256; off <<= 1) {
        int x = (t >= off) ? sd[t - off] : 0;
        __syncthreads();
        sd[t] += x;
        __syncthreads();
    }
    if (t < SCAN_BLK) blockSums[t] = sd[t] - v;   // exclusive
}

// ---------------------------------------------------------------------------
// 4) final scan: per-block exclusive scan + block offset -> offsets, cursor
// ---------------------------------------------------------------------------
__global__ void scan_final(const int* __restrict__ counts, const int* __restrict__ blockSums,
                           int* __restrict__ offsets, int* __restrict__ cursor)
{
    __shared__ int sd[256];
    int t = threadIdx.x, base = blockIdx.x * 1024 + t * 4;
    int c[4];
#pragma unroll
    for (int j = 0; j < 4; ++j) { int i = base + j; c[j] = (i < N_NODES) ? counts[i] : 0; }
    int tsum = c[0] + c[1] + c[2] + c[3];
    sd[t] = tsum; __syncthreads();
    for (int off = 1; off < 256; off <<= 1) {
        int x = (t >= off) ? sd[t - off] : 0;
        __syncthreads();
        sd[t] += x;
        __syncthreads();
    }
    int excl = sd[t] - tsum + blockSums[blockIdx.x];
#pragma unroll
    for (int j = 0; j < 4; ++j) {
        int i = base + j;
        if (i < N_NODES) { offsets[i] = excl; cursor[i] = excl; }
        excl += c[j];
    }
}

// ---------------------------------------------------------------------------
// 5) scatter event indices into CSR order
// ---------------------------------------------------------------------------
__global__ void scatter(const int* __restrict__ ids, int* __restrict__ cursor,
                        int* __restrict__ perm)
{
    int e = blockIdx.x * blockDim.x + threadIdx.x;
    if (e < E_EVENTS) {
        int pos = atomicAdd(cursor + ids[e], 1);
        perm[pos] = e;
    }
}

// ---------------------------------------------------------------------------
// 6) FUSED fat kernel.
//    seg waves: 13 consecutive nodes each, contiguous CSR event range,
//    8-deep independent row gathers, wave-uniform flush on node boundary.
//    attn waves: one b per wave, streaming.
//    Group of 17 blocks: 4 seg + 13 attn (ratio matches 3848:12506).
// ---------------------------------------------------------------------------
__global__ void __launch_bounds__(256, 8)
seg_attn(const int* __restrict__ perm, const int* __restrict__ offsets,
         const float* __restrict__ message, const float* __restrict__ ts,
         const float* __restrict__ nei1, const float* __restrict__ nei2,
         float* __restrict__ msg_out, float* __restrict__ t_out,
         float* __restrict__ logits)
{
    int g = blockIdx.x / 17, r = blockIdx.x % 17;
    int wid  = threadIdx.x >> 6;
    int lane = threadIdx.x & 63;

    if (r < 4) {
        // ---------------- segment gather-reduce ---------------------------------
        int wwid = (g * 4 + r) * 4 + wid;
        int n0 = wwid * NODES_PER_WAVE;
        if (n0 >= N_NODES) return;
        int nl = min(NODES_PER_WAVE, N_NODES - n0);
        // lane l (l<=nl) holds CSR boundary offsets[n0+l]; offsets[N] == E.
        int bnd = E_EVENTS;
        if (lane <= nl && n0 + lane < N_NODES) bnd = offsets[n0 + lane];
        int start = __shfl(bnd, 0);
        int end   = __shfl(bnd, nl);

        const float2* msg2 = reinterpret_cast<const float2*>(message);
        float2* out2 = reinterpret_cast<float2*>(msg_out);

        float2 acc = make_float2(0.f, 0.f);
        float tmax = 0.f;
        int node = 0;
        int nb = __shfl(bnd, 1);

        for (int base = start; base < end; base += 64) {
            int cl = min(end - base, 64);
            int e_l = 0; float t_l = 0.f;
            if (lane < cl) {
                e_l = perm[base + lane];
                t_l = ts[e_l];
            }
            for (int i0 = 0; i0 < 64; i0 += 8) {
                if (i0 >= cl) break;
                // issue 8 independent row gathers (static indices -> registers)
                float2 rr[8]; float tt[8];
#pragma unroll
                for (int j = 0; j < 8; ++j) {
                    int idx = i0 + j; if (idx >= cl) idx = cl - 1;   // clamp tail
                    int e  = __shfl(e_l, idx);
                    tt[j]  = __shfl(t_l, idx);
                    rr[j]  = msg2[(size_t)e * 64 + lane];
                }
#pragma unroll
                for (int j = 0; j < 8; ++j) {
                    if (i0 + j < cl) {
                        int i = base + i0 + j;
                        while (i == nb) {                 // flush finished node(s)
                            int lo = __shfl(bnd, node), hi = nb;
                            float inv = 1.0f / (float)max(hi - lo, 1);
                            out2[(size_t)(n0 + node) * 64 + lane] =
                                make_float2(acc.x * inv, acc.y * inv);
                            if (lane == 0) t_out[n0 + node] = tmax;
                            acc = make_float2(0.f, 0.f); tmax = 0.f;
                            ++node;
                            nb = __shfl(bnd, node + 1);
                        }
                        acc.x += rr[j].x; acc.y += rr[j].y;
                        tmax = fmaxf(tmax, tt[j]);
                    }
                }
            }
        }
        // flush remaining node(s) (last + trailing empties)
        while (node < nl) {
            int lo = __shfl(bnd, node), hi = __shfl(bnd, node + 1);
            float inv = 1.0f / (float)max(hi - lo, 1);
            out2[(size_t)(n0 + node) * 64 + lane] =
                make_float2(acc.x * inv, acc.y * inv);
            if (lane == 0) t_out[n0 + node] = tmax;
            acc = make_float2(0.f, 0.f); tmax = 0.f;
            ++node;
        }
    } else {
        // ---------------- attention logits: one wave per b ---------------------
        int ab = g * 13 + (r - 4);
        if (ab >= ATTN_BLOCKS) return;
        int b = ab * 4 + wid;
        int d4   = lane & 31;
        int half = lane >> 5;
        const float4* n2 = reinterpret_cast<const float4*>(nei2) + (size_t)b * (K_NEI * 32);
        float4 acc = make_float4(0.f, 0.f, 0.f, 0.f);
#pragma unroll
        for (int i = 0; i < K_NEI / 2; ++i) {
            float4 v = n2[(2 * i + half) * 32 + d4];
            acc.x += v.x; acc.y += v.y; acc.z += v.z; acc.w += v.w;
        }
        float4 s4;
        s4.x = acc.x + __shfl_xor(acc.x, 32);
        s4.y = acc.y + __shfl_xor(acc.y, 32);
        s4.z = acc.z + __shfl_xor(acc.z, 32);
        s4.w = acc.w + __shfl_xor(acc.w, 32);

        const float4* n1 = reinterpret_cast<const float4*>(nei1) + (size_t)b * (K_NEI * 32);
#pragma unroll
        for (int i = 0; i < K_NEI / 2; ++i) {
            int k = 2 * i + half;
            float4 v = n1[k * 32 + d4];
            float p = v.x * s4.x + v.y * s4.y + v.z * s4.z + v.w * s4.w;
#pragma unroll
            for (int off = 16; off; off >>= 1) p += __shfl_xor(p, off);
            if (d4 == 0) logits[(size_t)b * K_NEI + k] = p;
        }
    }
}

// ---------------------------------------------------------------------------
// 7) per-block online softmax partials over dim 0 (b). 128 blocks.
// ---------------------------------------------------------------------------
__global__ void softmax_partial(const float* __restrict__ logits, float2* __restrict__ partials)
{
    int t = threadIdx.x;
    float m[K_NEI], s[K_NEI];
#pragma unroll
    for (int k = 0; k < K_NEI; ++k) { m[k] = -INFINITY; s[k] = 0.f; }

    for (int b = blockIdx.x * 256 + t; b < B_BATCH; b += 128 * 256) {
        const float4* row = reinterpret_cast<const float4*>(logits + (size_t)b * K_NEI);
        float v[K_NEI];
#pragma unroll
        for (int q = 0; q < 5; ++q) {
            float4 rr = row[q];
            v[q * 4 + 0] = rr.x; v[q * 4 + 1] = rr.y; v[q * 4 + 2] = rr.z; v[q * 4 + 3] = rr.w;
        }
#pragma unroll
        for (int k = 0; k < K_NEI; ++k) {
            float nm = fmaxf(m[k], v[k]);
            s[k] = s[k] * expf(m[k] - nm) + expf(v[k] - nm);
            m[k] = nm;
        }
    }
#pragma unroll
    for (int k = 0; k < K_NEI; ++k) {
#pragma unroll
        for (int off = 32; off; off >>= 1) {
            float om = __shfl_xor(m[k], off);
            float os = __shfl_xor(s[k], off);
            float nm = fmaxf(m[k], om);
            s[k] = s[k] * expf(m[k] - nm) + os * expf(om - nm);
            m[k] = nm;
        }
    }
    __shared__ float lm[4][K_NEI], lsum[4][K_NEI];
    int wid = t >> 6, lane = t & 63;
    if (lane == 0) {
#pragma unroll
        for (int k = 0; k < K_NEI; ++k) { lm[wid][k] = m[k]; lsum[wid][k] = s[k]; }
    }
    __syncthreads();
    if (t < K_NEI) {
        float mm = lm[0][t], ss = lsum[0][t];
#pragma unroll
        for (int w = 1; w < 4; ++w) {
            float om = lm[w][t], os = lsum[w][t];
            float nm = fmaxf(mm, om);
            ss = ss * expf(mm - nm) + os * expf(om - nm);
            mm = nm;
        }
        partials[blockIdx.x * K_NEI + t] = make_float2(mm, ss);
    }
}

// ---------------------------------------------------------------------------
// 8) combine 128 partials -> stats[k]
// ---------------------------------------------------------------------------
__global__ void softmax_final(const float2* __restrict__ partials, float2* __restrict__ stats)
{
    int t = threadIdx.x;
    if (t < K_NEI) {
        float mm = -INFINITY, ss = 0.f;
        for (int i = 0; i < 128; ++i) {
            float2 p = partials[i * K_NEI + t];
            float nm = fmaxf(mm, p.x);
            ss = ss * expf(mm - nm) + p.y * expf(p.x - nm);
            mm = nm;
        }
        stats[t] = make_float2(mm, ss);
    }
}

// ---------------------------------------------------------------------------
// 9) normalize logits -> softmax scores
// ---------------------------------------------------------------------------
__global__ void softmax_norm(float* __restrict__ score, const float2* __restrict__ stats)
{
    int i = blockIdx.x * blockDim.x + threadIdx.x;
    if (i >= B_BATCH * K_NEI) return;
    int k = i % K_NEI;
    float2 st = stats[k];
    score[i] = expf(score[i] - st.x) / st.y;
}

extern "C" void kernel_launch(void* const* d_in, const int* in_sizes, int n_in,
                              void* d_out, int out_size, void* d_ws, size_t ws_size,
                              hipStream_t stream)
{
    const int*   node_ids = (const int*)  d_in[0];
    const float* message  = (const float*)d_in[1];
    const float* ts       = (const float*)d_in[2];
    const float* nei1     = (const float*)d_in[3];
    const float* nei2     = (const float*)d_in[4];

    float* out     = (float*)d_out;
    float* msg_out = out;                                   // [N,128]
    float* t_out   = out + (size_t)N_NODES * D_DIM;         // [N]
    float* score   = t_out + N_NODES;                       // [B,K]

    int*    wsi       = (int*)d_ws;
    int*    counts    = wsi;
    int*    offsets   = wsi + 200000;
    int*    cursor    = wsi + 400000;
    int*    blockSums = wsi + 600000;
    int*    perm      = wsi + 600320;
    float2* stats     = (float2*)(wsi + 1600320);
    float2* partials  = (float2*)(wsi + 1600384);

    hipMemsetAsync(counts, 0, (size_t)N_NODES * sizeof(int), stream);

    hist<<<(E_EVENTS + 255) / 256, 256, 0, stream>>>(node_ids, counts);
    scan_block<<<SCAN_BLK, 256, 0, stream>>>(counts, blockSums);
    scan_tops<<<1, 256, 0, stream>>>(blockSums);
    scan_final<<<SCAN_BLK, 256, 0, stream>>>(counts, blockSums, offsets, cursor);
    scatter<<<(E_EVENTS + 255) / 256, 256, 0, stream>>>(node_ids, cursor, perm);

    seg_attn<<<N_GROUPS * 17, 256, 0, stream>>>(
        perm, offsets, message, ts, nei1, nei2, msg_out, t_out, score);

    softmax_partial<<<128, 256, 0, stream>>>(score, partials);
    softmax_final<<<1, 64, 0, stream>>>(partials, stats);
    softmax_norm<<<(B_BATCH * K_NEI + 255) / 256, 256, 0, stream>>>(score, stats);
}

// Round 5
// 472.380 us; speedup vs baseline: 1.0698x; 1.0698x over previous
//
#include <hip/hip_runtime.h>

#define N_NODES 200000
#define E_EVENTS 1000000
#define D_DIM 128
#define B_BATCH 50000
#define K_NEI 20

#define SCAN_BLK 196              // ceil(200000/1024)

// ---------------- ws layout (element offsets, 4B units) --------------------
// counts   : [0,        200000)   int
// offsets  : [200000,   400000)   int
// cursor   : [400000,   600000)   int
// blockSums: [600000,   600256)   int
// stats    : [600256,   600320)   float2[20] (+pad)
// partials : [600320,   605440)   float2[128*20]
// perm     : [605440,   ...)      int[1M] (TSP=0) or int2[1M] (TSP=1)

// ---------------------------------------------------------------------------
// 1) histogram of node ids
// ---------------------------------------------------------------------------
__global__ void hist(const int* __restrict__ ids, int* __restrict__ counts)
{
    int e = blockIdx.x * blockDim.x + threadIdx.x;
    if (e < E_EVENTS) atomicAdd(counts + ids[e], 1);
}

// ---------------------------------------------------------------------------
// 2) per-block sums (1024 counts per block)
// ---------------------------------------------------------------------------
__global__ void scan_block(const int* __restrict__ counts, int* __restrict__ blockSums)
{
    __shared__ int sd[256];
    int t = threadIdx.x, base = blockIdx.x * 1024 + t * 4;
    int s = 0;
#pragma unroll
    for (int j = 0; j < 4; ++j) { int i = base + j; if (i < N_NODES) s += counts[i]; }
    sd[t] = s; __syncthreads();
    for (int off = 128; off; off >>= 1) {
        if (t < off) sd[t] += sd[t + off];
        __syncthreads();
    }
    if (t == 0) blockSums[blockIdx.x] = sd[0];
}

// ---------------------------------------------------------------------------
// 3) exclusive scan of the 196 block sums — one block, parallel.
// ---------------------------------------------------------------------------
__global__ void scan_tops(int* __restrict__ blockSums)
{
    __shared__ int sd[256];
    int t = threadIdx.x;
    int v = (t < SCAN_BLK) ? blockSums[t] : 0;
    sd[t] = v; __syncthreads();
    for (int off = 1; off < 256; off <<= 1) {
        int x = (t >= off) ? sd[t - off] : 0;
        __syncthreads();
        sd[t] += x;
        __syncthreads();
    }
    if (t < SCAN_BLK) blockSums[t] = sd[t] - v;   // exclusive
}

// ---------------------------------------------------------------------------
// 4) final scan: per-block exclusive scan + block offset -> offsets, cursor
// ---------------------------------------------------------------------------
__global__ void scan_final(const int* __restrict__ counts, const int* __restrict__ blockSums,
                           int* __restrict__ offsets, int* __restrict__ cursor)
{
    __shared__ int sd[256];
    int t = threadIdx.x, base = blockIdx.x * 1024 + t * 4;
    int c[4];
#pragma unroll
    for (int j = 0; j < 4; ++j) { int i = base + j; c[j] = (i < N_NODES) ? counts[i] : 0; }
    int tsum = c[0] + c[1] + c[2] + c[3];
    sd[t] = tsum; __syncthreads();
    for (int off = 1; off < 256; off <<= 1) {
        int x = (t >= off) ? sd[t - off] : 0;
        __syncthreads();
        sd[t] += x;
        __syncthreads();
    }
    int excl = sd[t] - tsum + blockSums[blockIdx.x];
#pragma unroll
    for (int j = 0; j < 4; ++j) {
        int i = base + j;
        if (i < N_NODES) { offsets[i] = excl; cursor[i] = excl; }
        excl += c[j];
    }
}

// ---------------------------------------------------------------------------
// 5) scatter event indices (and optionally ts) into CSR order
// ---------------------------------------------------------------------------
template<int TSP>
__global__ void scatter_t(const int* __restrict__ ids, const float* __restrict__ ts,
                          int* __restrict__ cursor, void* __restrict__ permv)
{
    int e = blockIdx.x * blockDim.x + threadIdx.x;
    if (e < E_EVENTS) {
        int pos = atomicAdd(cursor + ids[e], 1);
        if (TSP) ((int2*)permv)[pos] = make_int2(e, __float_as_int(ts[e]));
        else     ((int*)permv)[pos]  = e;
    }
}

// ---------------------------------------------------------------------------
// 6) FUSED fat kernel (R3 structure: 12500 groups x 5 blocks = 4 seg + 1 attn).
//    seg: one wave per node; half-wave-per-event paired float4 gathers.
//    attn: one wave per b; single 20-lane logits store.
// ---------------------------------------------------------------------------
template<int TSP>
__global__ void __launch_bounds__(256, 8)
seg_attn_t(const void* __restrict__ permv, const int* __restrict__ offsets,
           const float* __restrict__ message, const float* __restrict__ ts,
           const float* __restrict__ nei1, const float* __restrict__ nei2,
           float* __restrict__ msg_out, float* __restrict__ t_out,
           float* __restrict__ logits)
{
    int g = blockIdx.x / 5, r = blockIdx.x % 5;
    int wid  = threadIdx.x >> 6;
    int lane = threadIdx.x & 63;
    int c = lane & 31;      // float4 column within row
    int h = lane >> 5;      // half-wave id (event parity)

    if (r < 4) {
        // ---------------- segment gather-reduce: one wave per node -------------
        int n = (g * 4 + r) * 4 + wid;            // covers 200000 exactly
        int start = offsets[n];
        int end   = (n < N_NODES - 1) ? offsets[n + 1] : E_EVENTS;
        int len   = end - start;

        const float4* msg4 = reinterpret_cast<const float4*>(message);
        float4 acc0 = make_float4(0.f, 0.f, 0.f, 0.f);
        float4 acc1 = make_float4(0.f, 0.f, 0.f, 0.f);
        float tmax = 0.f;

        for (int base = start; base < end; base += 64) {
            int cl = min(end - base, 64);
            int e_l = 0; float t_l = 0.f;
            if (lane < cl) {
                if (TSP) {
                    int2 pe = ((const int2*)permv)[base + lane];
                    e_l = pe.x; t_l = __int_as_float(pe.y);
                } else {
                    e_l = ((const int*)permv)[base + lane];
                    t_l = ts[e_l];
                }
            }
            tmax = fmaxf(tmax, t_l);
            int i = 0;
            for (; i + 8 <= cl; i += 8) {         // 8 events, 4 paired loads
                int eA = __shfl(e_l, i + 0 + h);
                int eB = __shfl(e_l, i + 2 + h);
                int eC = __shfl(e_l, i + 4 + h);
                int eD = __shfl(e_l, i + 6 + h);
                float4 vA = msg4[(size_t)eA * 32 + c];
                float4 vB = msg4[(size_t)eB * 32 + c];
                float4 vC = msg4[(size_t)eC * 32 + c];
                float4 vD = msg4[(size_t)eD * 32 + c];
                acc0.x += vA.x; acc0.y += vA.y; acc0.z += vA.z; acc0.w += vA.w;
                acc1.x += vB.x; acc1.y += vB.y; acc1.z += vB.z; acc1.w += vB.w;
                acc0.x += vC.x; acc0.y += vC.y; acc0.z += vC.z; acc0.w += vC.w;
                acc1.x += vD.x; acc1.y += vD.y; acc1.z += vD.z; acc1.w += vD.w;
            }
            for (; i + 2 <= cl; i += 2) {         // 2 events, 1 paired load
                int e = __shfl(e_l, i + h);
                float4 v = msg4[(size_t)e * 32 + c];
                acc0.x += v.x; acc0.y += v.y; acc0.z += v.z; acc0.w += v.w;
            }
            if (i < cl) {                          // 1 trailing event, half 0 only
                int e = __shfl(e_l, i);
                if (h == 0) {
                    float4 v = msg4[(size_t)e * 32 + c];
                    acc0.x += v.x; acc0.y += v.y; acc0.z += v.z; acc0.w += v.w;
                }
            }
        }
        // combine pair-slots, then cross-half add (dims are same per half)
        float4 acc = make_float4(acc0.x + acc1.x, acc0.y + acc1.y,
                                 acc0.z + acc1.z, acc0.w + acc1.w);
        acc.x += __shfl_xor(acc.x, 32);
        acc.y += __shfl_xor(acc.y, 32);
        acc.z += __shfl_xor(acc.z, 32);
        acc.w += __shfl_xor(acc.w, 32);
        float inv = 1.0f / (float)max(len, 1);
        if (h == 0) {
            reinterpret_cast<float4*>(msg_out)[(size_t)n * 32 + c] =
                make_float4(acc.x * inv, acc.y * inv, acc.z * inv, acc.w * inv);
        }
#pragma unroll
        for (int off = 32; off; off >>= 1) tmax = fmaxf(tmax, __shfl_xor(tmax, off));
        if (lane == 0) t_out[n] = tmax;
    } else {
        // ---------------- attention logits: one wave per b ---------------------
        int b = g * 4 + wid;                      // covers 50000 exactly
        const float4* n2 = reinterpret_cast<const float4*>(nei2) + (size_t)b * (K_NEI * 32);
        float4 acc = make_float4(0.f, 0.f, 0.f, 0.f);
#pragma unroll
        for (int i = 0; i < K_NEI / 2; ++i) {
            float4 v = n2[(2 * i + h) * 32 + c];
            acc.x += v.x; acc.y += v.y; acc.z += v.z; acc.w += v.w;
        }
        float4 s4;
        s4.x = acc.x + __shfl_xor(acc.x, 32);
        s4.y = acc.y + __shfl_xor(acc.y, 32);
        s4.z = acc.z + __shfl_xor(acc.z, 32);
        s4.w = acc.w + __shfl_xor(acc.w, 32);

        const float4* n1 = reinterpret_cast<const float4*>(nei1) + (size_t)b * (K_NEI * 32);
        float p[K_NEI / 2];
#pragma unroll
        for (int i = 0; i < K_NEI / 2; ++i) {
            float4 v = n1[(2 * i + h) * 32 + c];
            float pp = v.x * s4.x + v.y * s4.y + v.z * s4.z + v.w * s4.w;
#pragma unroll
            for (int off = 16; off; off >>= 1) pp += __shfl_xor(pp, off);
            p[i] = pp;   // all 32 lanes of half h hold logit for k = 2*i + h
        }
        // lane c<20 wants k=c: parity c&1 lives in half c&1 at slot c>>1.
        int sel = c >> 1;
        float v = p[0];
#pragma unroll
        for (int i = 1; i < K_NEI / 2; ++i) v = (sel == i) ? p[i] : v;
        float vf = __shfl(v, ((lane & 1) << 5) + c);
        if (lane < K_NEI) logits[(size_t)b * K_NEI + lane] = vf;
    }
}

// ---------------------------------------------------------------------------
// 7) per-block online softmax partials over dim 0 (b). 128 blocks.
// ---------------------------------------------------------------------------
__global__ void softmax_partial(const float* __restrict__ logits, float2* __restrict__ partials)
{
    int t = threadIdx.x;
    float m[K_NEI], s[K_NEI];
#pragma unroll
    for (int k = 0; k < K_NEI; ++k) { m[k] = -INFINITY; s[k] = 0.f; }

    for (int b = blockIdx.x * 256 + t; b < B_BATCH; b += 128 * 256) {
        const float4* row = reinterpret_cast<const float4*>(logits + (size_t)b * K_NEI);
        float v[K_NEI];
#pragma unroll
        for (int q = 0; q < 5; ++q) {
            float4 rr = row[q];
            v[q * 4 + 0] = rr.x; v[q * 4 + 1] = rr.y; v[q * 4 + 2] = rr.z; v[q * 4 + 3] = rr.w;
        }
#pragma unroll
        for (int k = 0; k < K_NEI; ++k) {
            float nm = fmaxf(m[k], v[k]);
            s[k] = s[k] * expf(m[k] - nm) + expf(v[k] - nm);
            m[k] = nm;
        }
    }
#pragma unroll
    for (int k = 0; k < K_NEI; ++k) {
#pragma unroll
        for (int off = 32; off; off >>= 1) {
            float om = __shfl_xor(m[k], off);
            float os = __shfl_xor(s[k], off);
            float nm = fmaxf(m[k], om);
            s[k] = s[k] * expf(m[k] - nm) + os * expf(om - nm);
            m[k] = nm;
        }
    }
    __shared__ float lm[4][K_NEI], lsum[4][K_NEI];
    int wid = t >> 6, lane = t & 63;
    if (lane == 0) {
#pragma unroll
        for (int k = 0; k < K_NEI; ++k) { lm[wid][k] = m[k]; lsum[wid][k] = s[k]; }
    }
    __syncthreads();
    if (t < K_NEI) {
        float mm = lm[0][t], ss = lsum[0][t];
#pragma unroll
        for (int w = 1; w < 4; ++w) {
            float om = lm[w][t], os = lsum[w][t];
            float nm = fmaxf(mm, om);
            ss = ss * expf(mm - nm) + os * expf(om - nm);
            mm = nm;
        }
        partials[blockIdx.x * K_NEI + t] = make_float2(mm, ss);
    }
}

// ---------------------------------------------------------------------------
// 8) combine 128 partials -> stats[k]
// ---------------------------------------------------------------------------
__global__ void softmax_final(const float2* __restrict__ partials, float2* __restrict__ stats)
{
    int t = threadIdx.x;
    if (t < K_NEI) {
        float mm = -INFINITY, ss = 0.f;
        for (int i = 0; i < 128; ++i) {
            float2 p = partials[i * K_NEI + t];
            float nm = fmaxf(mm, p.x);
            ss = ss * expf(mm - nm) + p.y * expf(p.x - nm);
            mm = nm;
        }
        stats[t] = make_float2(mm, ss);
    }
}

// ---------------------------------------------------------------------------
// 9) normalize logits -> softmax scores
// ---------------------------------------------------------------------------
__global__ void softmax_norm(float* __restrict__ score, const float2* __restrict__ stats)
{
    int i = blockIdx.x * blockDim.x + threadIdx.x;
    if (i >= B_BATCH * K_NEI) return;
    int k = i % K_NEI;
    float2 st = stats[k];
    score[i] = expf(score[i] - st.x) / st.y;
}

extern "C" void kernel_launch(void* const* d_in, const int* in_sizes, int n_in,
                              void* d_out, int out_size, void* d_ws, size_t ws_size,
                              hipStream_t stream)
{
    const int*   node_ids = (const int*)  d_in[0];
    const float* message  = (const float*)d_in[1];
    const float* ts       = (const float*)d_in[2];
    const float* nei1     = (const float*)d_in[3];
    const float* nei2     = (const float*)d_in[4];

    float* out     = (float*)d_out;
    float* msg_out = out;                                   // [N,128]
    float* t_out   = out + (size_t)N_NODES * D_DIM;         // [N]
    float* score   = t_out + N_NODES;                       // [B,K]

    int*    wsi       = (int*)d_ws;
    int*    counts    = wsi;
    int*    offsets   = wsi + 200000;
    int*    cursor    = wsi + 400000;
    int*    blockSums = wsi + 600000;
    float2* stats     = (float2*)(wsi + 600256);
    float2* partials  = (float2*)(wsi + 600320);
    void*   permv     = (void*)(wsi + 605440);

    // int2 perm (event, ts) needs 605440*4 + 8M bytes
    bool tsp = ws_size >= ((size_t)605440 * 4 + (size_t)E_EVENTS * 8);

    hipMemsetAsync(counts, 0, (size_t)N_NODES * sizeof(int), stream);

    hist<<<(E_EVENTS + 255) / 256, 256, 0, stream>>>(node_ids, counts);
    scan_block<<<SCAN_BLK, 256, 0, stream>>>(counts, blockSums);
    scan_tops<<<1, 256, 0, stream>>>(blockSums);
    scan_final<<<SCAN_BLK, 256, 0, stream>>>(counts, blockSums, offsets, cursor);

    if (tsp) {
        scatter_t<1><<<(E_EVENTS + 255) / 256, 256, 0, stream>>>(node_ids, ts, cursor, permv);
        seg_attn_t<1><<<12500 * 5, 256, 0, stream>>>(
            permv, offsets, message, ts, nei1, nei2, msg_out, t_out, score);
    } else {
        scatter_t<0><<<(E_EVENTS + 255) / 256, 256, 0, stream>>>(node_ids, ts, cursor, permv);
        seg_attn_t<0><<<12500 * 5, 256, 0, stream>>>(
            permv, offsets, message, ts, nei1, nei2, msg_out, t_out, score);
    }

    softmax_partial<<<128, 256, 0, stream>>>(score, partials);
    softmax_final<<<1, 64, 0, stream>>>(partials, stats);
    softmax_norm<<<(B_BATCH * K_NEI + 255) / 256, 256, 0, stream>>>(score, stats);
}